// Round 6
// baseline (359.445 us; speedup 1.0000x reference)
//
#include <hip/hip_runtime.h>

// LinearFlexQMixer MI355X — round 6.
// R5 cooperative launch broke the harness -> back to 2 regular launches.
// Fix 1: prep kernel now iterates over SOURCE elements (coalesced fp32 reads,
//   scattered 2B bf16 writes) instead of destination order (scattered 4B
//   gather reads, ~105us latency-bound).
// Fix 2: __launch_bounds__(256,2) (R3's no-spill cap) + R4's 53KB LDS
//   overlays -> 3 blocks/CU from actual VGPR usage, no spills.

#define NA 16
#define NEn 128
#define EDm 96
#define ST 136  // LDS row stride (shorts); 272B rows -> <=2-way conflicts

typedef __attribute__((ext_vector_type(8))) short bf16x8;
typedef __attribute__((ext_vector_type(4))) float f32x4;

#define MFMA(a, b, c) __builtin_amdgcn_mfma_f32_16x16x32_bf16((a), (b), (c), 0, 0, 0)

// d_ws layout (bf16 elems), per hypernet p at p*HYPE:
#define OFF_W1 0       // [nt8][kt3][64][8]  B-frags Phase A (fc1w)
#define OFF_WQ 12288   // [nt8][kt4][64][8]  B-frags Q (inw cols 0:128, pre-scaled)
#define OFF_WK 28672   // [h4][nt8][64][8]   B-frags qW (Wk^T per head, K=32)
#define OFF_WV 45056   // [h4][mt2][kt4][64][8] A-frags V^T (Wv^T per head)
#define OFF_WO 61440   // [nt8][kt4][64][8]  B-frags OUT (outw)
#define OFF_W2 77824   // [nt2][kt4][64][8]  B-frags X3 (fc2w)
#define HYPE 81920
#define WS_FLAG_OFF 327680  // int flag: mask dtype (1 => int32)

__device__ __forceinline__ unsigned short f2bf(float f) {
  unsigned u = __float_as_uint(f);
  u += 0x7fffu + ((u >> 16) & 1u);  // RNE
  return (unsigned short)(u >> 16);
}

// Store one 16x16 C-tile column (4 f32, rows row0+0..3, col) as bf16 into
// LDS row-major [..][ST]. Pairs lanes (col, col^1) via shfl so every dword
// is written by exactly one lane.
__device__ __forceinline__ void ctile_store(unsigned short* dst, int row0,
                                            int col, f32x4 v) {
  unsigned short m0 = f2bf(v[0]), m1 = f2bf(v[1]), m2 = f2bf(v[2]),
                 m3 = f2bf(v[3]);
  unsigned x = (unsigned)m0 | ((unsigned)m1 << 16);
  unsigned y = (unsigned)m2 | ((unsigned)m3 << 16);
  unsigned ox = (unsigned)__shfl_xor((int)x, 1);
  unsigned oy = (unsigned)__shfl_xor((int)y, 1);
  unsigned w0, w1;
  int ra;
  if ((threadIdx.x & 1) == 0) {
    ra = 0;
    w0 = (x & 0xffffu) | (ox << 16);
    w1 = (x >> 16) | (ox & 0xffff0000u);
  } else {
    ra = 2;
    w0 = (oy & 0xffffu) | (y << 16);
    w1 = (oy >> 16) | (y & 0xffff0000u);
  }
  *(unsigned*)(dst + (row0 + ra) * ST + (col & ~1)) = w0;
  *(unsigned*)(dst + (row0 + ra + 1) * ST + (col & ~1)) = w1;
}

// ---- prep: SOURCE-order iteration (coalesced reads, scattered writes) ----
// Block 640 additionally does the mask-dtype scan.
__global__ void prep_kernel(const float* __restrict__ w_fc1w,
                            const float* __restrict__ w_inw,
                            const float* __restrict__ w_outw,
                            const float* __restrict__ w_fc2w,
                            const float* __restrict__ v_fc1w,
                            const float* __restrict__ v_inw,
                            const float* __restrict__ v_outw,
                            const float* __restrict__ v_fc2w,
                            const unsigned char* __restrict__ mask,
                            unsigned short* __restrict__ ws,
                            int* __restrict__ flag) {
  if (blockIdx.x == 2 * HYPE / 256) {
    // int32 0/1 data => every byte at offset %4!=0 is zero over first 4KB.
    const uint4 v = *(const uint4*)(mask + threadIdx.x * 16);
    const unsigned nz = (v.x | v.y | v.z | v.w) & 0xffffff00u;
    const int any = __syncthreads_or((int)(nz != 0));
    if (threadIdx.x == 0) *flag = (any == 0) ? 1 : 0;
    return;
  }
  const int g = blockIdx.x * 256 + threadIdx.x;  // 0 .. 163839, source order
  const int p = g / HYPE;
  const int off = g - p * HYPE;
  const float* fc1w = p ? v_fc1w : w_fc1w;
  const float* inw = p ? v_inw : w_inw;
  const float* outw = p ? v_outw : w_outw;
  const float* fc2w = p ? v_fc2w : w_fc2w;
  float val;
  int dest;
  if (off < OFF_WQ) {
    // fc1w [96][128] row-major; coalesced read.
    const int k = off >> 7, n = off & 127;
    val = fc1w[off];
    const int kt = k >> 5, kr = k & 31, j = kr & 7, khi = kr >> 3;
    const int nt = n >> 4, lo = n & 15;
    dest = OFF_W1 + (nt * 3 + kt) * 512 + (khi * 16 + lo) * 8 + j;
  } else if (off < OFF_WK) {
    // inw cols [0,128) (Wq), rows k in [0,128); coalesced per row.
    const int i = off - OFF_WQ;
    const int k = i >> 7, n = i & 127;
    val = inw[k * 384 + n] * 0.17677669529663687f;
    const int kt = k >> 5, kr = k & 31, j = kr & 7, khi = kr >> 3;
    const int nt = n >> 4, lo = n & 15;
    dest = OFF_WQ + (nt * 4 + kt) * 512 + (khi * 16 + lo) * 8 + j;
  } else if (off < OFF_WV) {
    // inw cols [128,256) (Wk), rows m; B-frag of Wk^T per head.
    const int i = off - OFF_WK;
    const int m = i >> 7, c = i & 127;
    val = inw[m * 384 + 128 + c];
    const int h = c >> 5, d = c & 31;
    const int nt = m >> 4;
    const int l = (d >> 3) * 16 + (m & 15);
    dest = OFF_WK + (h * 8 + nt) * 512 + l * 8 + (d & 7);
  } else if (off < OFF_WO) {
    // inw cols [256,384) (Wv), rows m; A-frag of Wv^T per head.
    const int i = off - OFF_WV;
    const int m = i >> 7, c = i & 127;
    val = inw[m * 384 + 256 + c];
    const int h = c >> 5, d = c & 31;
    const int kt = m >> 5, mr = m & 31, j = mr & 7, mhi = mr >> 3;
    const int mt = d >> 4, lo = d & 15;
    dest = OFF_WV + ((h * 2 + mt) * 4 + kt) * 512 + (mhi * 16 + lo) * 8 + j;
  } else if (off < OFF_W2) {
    // outw [128][128]; coalesced.
    const int i = off - OFF_WO;
    const int k = i >> 7, n = i & 127;
    val = outw[i];
    const int kt = k >> 5, kr = k & 31, j = kr & 7, khi = kr >> 3;
    const int nt = n >> 4, lo = n & 15;
    dest = OFF_WO + (nt * 4 + kt) * 512 + (khi * 16 + lo) * 8 + j;
  } else {
    // fc2w [128][32]; coalesced.
    const int i = off - OFF_W2;
    const int k = i >> 5, n = i & 31;
    val = fc2w[i];
    const int kt = k >> 5, kr = k & 31, j = kr & 7, khi = kr >> 3;
    const int nt = n >> 4, lo = n & 15;
    dest = OFF_W2 + (nt * 4 + kt) * 512 + (khi * 16 + lo) * 8 + j;
  }
  ws[p * HYPE + dest] = f2bf(val);
}

// LDS (bytes), ~52.0 KB -> 3 blocks/CU:
//   sx1 [128][136]bf16  0..34816
//   sVT [32][136]       34816..43520
//   sQA [16][136]       43520..47872   (Q, then attn accumulator)
//   sSC [16][136]       47872..52224   (qW -> W -> out, time-sliced)
//   sred f2[64]         52224..52736
//   sres f32[32]        52736..52864
//   sm  u8[128]         52864..52992
#define SMEM_BYTES 52992

__global__ __launch_bounds__(256, 2) void qmix_mfma(
    const float* __restrict__ agent_qs, const float* __restrict__ entities,
    const unsigned char* __restrict__ emask_g,
    const unsigned short* __restrict__ wsw, const int* __restrict__ mflag,
    const float* __restrict__ w_fc1b, const float* __restrict__ w_outb,
    const float* __restrict__ w_fc2b, const float* __restrict__ v_fc1b,
    const float* __restrict__ v_outb, const float* __restrict__ v_fc2b,
    float* __restrict__ out_g) {
  const int t = threadIdx.x;
  const int wv = t >> 6;
  const int ln = t & 63;
  const int lr = ln & 15;
  const int lq = ln >> 4;
  const int b = blockIdx.x;
  const float* ents = entities + (size_t)b * (NEn * EDm);

  __shared__ __align__(16) unsigned char smem[SMEM_BYTES];
  unsigned short* sx1 = (unsigned short*)smem;
  unsigned short* sVT = sx1 + 17408;
  unsigned short* sQA = sx1 + 21760;  // Q, then attn
  unsigned short* sSC = sx1 + 23936;  // qW -> W -> out
  float2* sred = (float2*)(smem + 52224);
  float* sredf = (float*)(smem + 52224);
  float* sres = (float*)(smem + 52736);
  unsigned char* sm = smem + 52864;

  // ---- entity mask (dtype-normalized) ----
  const int is_i32 = *mflag;
  int mv = 1;
  if (t < NEn) {
    if (is_i32)
      mv = (((const int*)emask_g)[(size_t)b * NEn + t] != 0) ? 1 : 0;
    else
      mv = (emask_g[(size_t)b * NEn + t] != 0) ? 1 : 0;
    sm[t] = (unsigned char)mv;
  }
  const int allE = __syncthreads_and(mv);

  for (int p = 0; p < 2; ++p) {
    const unsigned short* wsb = wsw + (size_t)p * HYPE;
    const float* fc1b = p ? v_fc1b : w_fc1b;
    const float* outb = p ? v_outb : w_outb;
    const float* fc2b = p ? v_fc2b : w_fc2b;

    // ---- Phase A: x1 = relu(E @ W1 + b) -> sx1 bf16 [e][m] ----
    {
#pragma unroll
      for (int mi = 0; mi < 2; ++mi) {
        const int mt = wv * 2 + mi;
        bf16x8 af[3];
        const float* erow = ents + (mt * 16 + lr) * EDm + lq * 8;
#pragma unroll
        for (int kt = 0; kt < 3; ++kt) {
          float4 u = *(const float4*)(erow + kt * 32);
          float4 v = *(const float4*)(erow + kt * 32 + 4);
          bf16x8 a;
          a[0] = (short)f2bf(u.x); a[1] = (short)f2bf(u.y);
          a[2] = (short)f2bf(u.z); a[3] = (short)f2bf(u.w);
          a[4] = (short)f2bf(v.x); a[5] = (short)f2bf(v.y);
          a[6] = (short)f2bf(v.z); a[7] = (short)f2bf(v.w);
          af[kt] = a;
        }
        for (int nt = 0; nt < 8; ++nt) {
          f32x4 acc = {0.f, 0.f, 0.f, 0.f};
          const unsigned short* bp = wsb + OFF_W1 + (nt * 3) * 512 + ln * 8;
#pragma unroll
          for (int kt = 0; kt < 3; ++kt)
            acc = MFMA(af[kt], *(const bf16x8*)(bp + kt * 512), acc);
          const float bias = fc1b[nt * 16 + lr];
          f32x4 r;
          r[0] = fmaxf(acc[0] + bias, 0.f); r[1] = fmaxf(acc[1] + bias, 0.f);
          r[2] = fmaxf(acc[2] + bias, 0.f); r[3] = fmaxf(acc[3] + bias, 0.f);
          ctile_store(sx1, mt * 16 + lq * 4, nt * 16 + lr, r);
        }
      }
    }
    __syncthreads();

    // ---- Q = x1[0:16] @ Wq' (scaled) -> sQA [16][128] ----
    {
      bf16x8 aq[4];
#pragma unroll
      for (int kt = 0; kt < 4; ++kt)
        aq[kt] = *(const bf16x8*)(sx1 + lr * ST + kt * 32 + lq * 8);
#pragma unroll
      for (int ni = 0; ni < 2; ++ni) {
        const int nt = wv * 2 + ni;
        f32x4 acc = {0.f, 0.f, 0.f, 0.f};
        const unsigned short* bp = wsb + OFF_WQ + (nt * 4) * 512 + ln * 8;
#pragma unroll
        for (int kt = 0; kt < 4; ++kt)
          acc = MFMA(aq[kt], *(const bf16x8*)(bp + kt * 512), acc);
        ctile_store(sQA, lq * 4, nt * 16 + lr, acc);
      }
    }
    __syncthreads();

    // Preload all-head Q A-frags; frees sQA for the attn accumulator.
    bf16x8 aQh[4];
#pragma unroll
    for (int h = 0; h < 4; ++h)
      aQh[h] = *(const bf16x8*)(sQA + lr * ST + h * 32 + lq * 8);

    for (int h = 0; h < 4; ++h) {
      // ---- merged: qW = Q_h @ Wk_h^T -> sSC, V^T_h = Wv_h^T @ x1^T -> sVT
      {
#pragma unroll
        for (int ni = 0; ni < 2; ++ni) {
          const int nt = wv * 2 + ni;
          bf16x8 bk =
              *(const bf16x8*)(wsb + OFF_WK + (h * 8 + nt) * 512 + ln * 8);
          f32x4 acc = {0.f, 0.f, 0.f, 0.f};
          acc = MFMA(aQh[h], bk, acc);
          ctile_store(sSC, lq * 4, nt * 16 + lr, acc);
        }
        bf16x8 av[2][4];
#pragma unroll
        for (int mt = 0; mt < 2; ++mt)
#pragma unroll
          for (int kt = 0; kt < 4; ++kt)
            av[mt][kt] = *(const bf16x8*)(wsb + OFF_WV +
                                          (((h * 2 + mt) * 4) + kt) * 512 +
                                          ln * 8);
#pragma unroll
        for (int ni = 0; ni < 2; ++ni) {
          const int nt = wv * 2 + ni;
          bf16x8 bx[4];
#pragma unroll
          for (int kt = 0; kt < 4; ++kt)
            bx[kt] =
                *(const bf16x8*)(sx1 + (nt * 16 + lr) * ST + kt * 32 + lq * 8);
#pragma unroll
          for (int mt = 0; mt < 2; ++mt) {
            f32x4 acc = {0.f, 0.f, 0.f, 0.f};
#pragma unroll
            for (int kt = 0; kt < 4; ++kt) acc = MFMA(av[mt][kt], bx[kt], acc);
            ctile_store(sVT, mt * 16 + lq * 4, nt * 16 + lr, acc);
          }
        }
      }
      __syncthreads();

      // ---- logits = qW @ x1^T, mask cols, wave-local softmax stats ----
      float mx[4], ex0[4], ex1[4];
      {
        bf16x8 aw[4];
#pragma unroll
        for (int kt = 0; kt < 4; ++kt)
          aw[kt] = *(const bf16x8*)(sSC + lr * ST + kt * 32 + lq * 8);
        f32x4 a0 = {0.f, 0.f, 0.f, 0.f}, a1 = {0.f, 0.f, 0.f, 0.f};
        const int nt0 = wv * 2, nt1 = nt0 + 1;
#pragma unroll
        for (int kt = 0; kt < 4; ++kt) {
          bf16x8 b0 =
              *(const bf16x8*)(sx1 + (nt0 * 16 + lr) * ST + kt * 32 + lq * 8);
          bf16x8 b1 =
              *(const bf16x8*)(sx1 + (nt1 * 16 + lr) * ST + kt * 32 + lq * 8);
          a0 = MFMA(aw[kt], b0, a0);
          a1 = MFMA(aw[kt], b1, a1);
        }
        const int e0m = sm[nt0 * 16 + lr], e1m = sm[nt1 * 16 + lr];
        float l0[4], l1[4];
#pragma unroll
        for (int r = 0; r < 4; ++r) {
          l0[r] = e0m ? -1e9f : a0[r];
          l1[r] = e1m ? -1e9f : a1[r];
          mx[r] = fmaxf(l0[r], l1[r]);
        }
#pragma unroll
        for (int k = 1; k < 16; k <<= 1)
#pragma unroll
          for (int r = 0; r < 4; ++r)
            mx[r] = fmaxf(mx[r], __shfl_xor(mx[r], k));
        float sl[4];
#pragma unroll
        for (int r = 0; r < 4; ++r) {
          ex0[r] = __expf(l0[r] - mx[r]);
          ex1[r] = __expf(l1[r] - mx[r]);
          sl[r] = ex0[r] + ex1[r];
        }
#pragma unroll
        for (int k = 1; k < 16; k <<= 1)
#pragma unroll
          for (int r = 0; r < 4; ++r) sl[r] += __shfl_xor(sl[r], k);
        if (lr == 0) {
#pragma unroll
          for (int r = 0; r < 4; ++r)
            sred[wv * 16 + lq * 4 + r] = make_float2(mx[r], sl[r]);
        }
      }
      __syncthreads();

      // ---- softmax finish -> sSC (overwrites qW; aw consumed) ----
      {
        f32x4 w0v, w1v;
#pragma unroll
        for (int r = 0; r < 4; ++r) {
          const int row = lq * 4 + r;
          float2 p0 = sred[row], p1 = sred[16 + row], p2 = sred[32 + row],
                 p3 = sred[48 + row];
          float M = fmaxf(fmaxf(p0.x, p1.x), fmaxf(p2.x, p3.x));
          float S = __expf(p0.x - M) * p0.y + __expf(p1.x - M) * p1.y +
                    __expf(p2.x - M) * p2.y + __expf(p3.x - M) * p3.y;
          const float sc = ((int)sm[row] | allE) ? 0.f : (1.f / S);
          const float f = __expf(mx[r] - M) * sc;
          w0v[r] = ex0[r] * f;
          w1v[r] = ex1[r] * f;
        }
        ctile_store(sSC, lq * 4, wv * 32 + lr, w0v);
        ctile_store(sSC, lq * 4, wv * 32 + 16 + lr, w1v);
      }
      __syncthreads();

      // ---- attn_h = w @ V_h -> sQA cols h*32.. (waves 0,1) ----
      if (wv < 2) {
        bf16x8 afr[4];
#pragma unroll
        for (int kt = 0; kt < 4; ++kt)
          afr[kt] = *(const bf16x8*)(sSC + lr * ST + kt * 32 + lq * 8);
        f32x4 acc = {0.f, 0.f, 0.f, 0.f};
#pragma unroll
        for (int kt = 0; kt < 4; ++kt) {
          bf16x8 bfr =
              *(const bf16x8*)(sVT + (wv * 16 + lr) * ST + kt * 32 + lq * 8);
          acc = MFMA(afr[kt], bfr, acc);
        }
        ctile_store(sQA, lq * 4, h * 32 + wv * 16 + lr, acc);
      }
      __syncthreads();
    }  // heads

    // ---- OUT = attn @ Wo + bo -> sSC ----
    {
      bf16x8 aa[4];
#pragma unroll
      for (int kt = 0; kt < 4; ++kt)
        aa[kt] = *(const bf16x8*)(sQA + lr * ST + kt * 32 + lq * 8);
#pragma unroll
      for (int ni = 0; ni < 2; ++ni) {
        const int nt = wv * 2 + ni;
        f32x4 acc = {0.f, 0.f, 0.f, 0.f};
        const unsigned short* bp = wsb + OFF_WO + (nt * 4) * 512 + ln * 8;
#pragma unroll
        for (int kt = 0; kt < 4; ++kt)
          acc = MFMA(aa[kt], *(const bf16x8*)(bp + kt * 512), acc);
        const float bj = outb[nt * 16 + lr];
        f32x4 r;
        r[0] = acc[0] + bj; r[1] = acc[1] + bj;
        r[2] = acc[2] + bj; r[3] = acc[3] + bj;
        ctile_store(sSC, lq * 4, nt * 16 + lr, r);
      }
    }
    __syncthreads();

    // ---- X3 = out @ fc2 + b, mask rows, row-sum (waves 0,1) ----
    if (wv < 2) {
      bf16x8 ao[4];
#pragma unroll
      for (int kt = 0; kt < 4; ++kt)
        ao[kt] = *(const bf16x8*)(sSC + lr * ST + kt * 32 + lq * 8);
      f32x4 acc = {0.f, 0.f, 0.f, 0.f};
      const unsigned short* bp = wsb + OFF_W2 + (wv * 4) * 512 + ln * 8;
#pragma unroll
      for (int kt = 0; kt < 4; ++kt)
        acc = MFMA(ao[kt], *(const bf16x8*)(bp + kt * 512), acc);
      const float bc = fc2b[wv * 16 + lr];
      float rs[4];
#pragma unroll
      for (int r = 0; r < 4; ++r) {
        const int row = lq * 4 + r;
        rs[r] = sm[row] ? 0.f : (acc[r] + bc);
      }
#pragma unroll
      for (int k = 1; k < 16; k <<= 1)
#pragma unroll
        for (int r = 0; r < 4; ++r) rs[r] += __shfl_xor(rs[r], k);
      if (lr == 0) {
#pragma unroll
        for (int r = 0; r < 4; ++r) sredf[wv * 16 + lq * 4 + r] = rs[r];
      }
    }
    __syncthreads();
    if (t < 16) {
      const float s = sredf[t] + sredf[16 + t];
      if (p == 0)
        sres[t] = fabsf(s) * (1.f / 32.f);
      else
        sres[16 + t] = s;
    }
    __syncthreads();
  }  // p

  if (t == 0) {
    const float* qs = agent_qs + (size_t)b * NA;
    float tot = 0.f, vs = 0.f;
#pragma unroll
    for (int q = 0; q < NA; ++q) {
      tot += qs[q] * sres[q];
      vs += sres[16 + q];
    }
    out_g[b] = tot + vs * (1.f / 512.f);
  }
}

extern "C" void kernel_launch(void* const* d_in, const int* in_sizes, int n_in,
                              void* d_out, int out_size, void* d_ws,
                              size_t ws_size, hipStream_t stream) {
  (void)n_in; (void)out_size; (void)ws_size;
  const int nb = in_sizes[0] / NA;  // BS*T = 1600
  unsigned short* wsw = (unsigned short*)d_ws;
  int* mflag = (int*)((char*)d_ws + WS_FLAG_OFF);

  hipLaunchKernelGGL(prep_kernel, dim3(2 * HYPE / 256 + 1), dim3(256), 0,
                     stream, (const float*)d_in[3], (const float*)d_in[5],
                     (const float*)d_in[6], (const float*)d_in[8],
                     (const float*)d_in[10], (const float*)d_in[12],
                     (const float*)d_in[13], (const float*)d_in[15],
                     (const unsigned char*)d_in[2], wsw, mflag);
  hipLaunchKernelGGL(qmix_mfma, dim3(nb), dim3(256), 0, stream,
                     (const float*)d_in[0], (const float*)d_in[1],
                     (const unsigned char*)d_in[2], (const unsigned short*)wsw,
                     (const int*)mflag, (const float*)d_in[4],
                     (const float*)d_in[7], (const float*)d_in[9],
                     (const float*)d_in[11], (const float*)d_in[14],
                     (const float*)d_in[16], (float*)d_out);
}

// Round 7
// 302.270 us; speedup vs baseline: 1.1892x; 1.1892x over previous
//
#include <hip/hip_runtime.h>

// LinearFlexQMixer MI355X — round 7.
// Main kernel: exact R3 structure (measured 198us, no overlays — R4/R6's
// overlay variant regressed to ~250us at identical counters).
// Prep kernel: minimal — 160 blocks, one coalesced float4 read + 4 scattered
// 2B writes per thread (source-order), + 1 mask-scan block.

#define NA 16
#define NEn 128
#define EDm 96
#define ST 136  // LDS row stride (shorts); 272B rows -> <=2-way conflicts

typedef __attribute__((ext_vector_type(8))) short bf16x8;
typedef __attribute__((ext_vector_type(4))) float f32x4;

#define MFMA(a, b, c) __builtin_amdgcn_mfma_f32_16x16x32_bf16((a), (b), (c), 0, 0, 0)

// d_ws layout (bf16 elems), per hypernet p at p*HYPE:
#define OFF_W1 0       // [nt8][kt3][64][8]  B-frags Phase A (fc1w)
#define OFF_WQ 12288   // [nt8][kt4][64][8]  B-frags Q (inw cols 0:128, pre-scaled)
#define OFF_WK 28672   // [h4][nt8][64][8]   B-frags qW (Wk^T per head, K=32)
#define OFF_WV 45056   // [h4][mt2][kt4][64][8] A-frags V^T (Wv^T per head)
#define OFF_WO 61440   // [nt8][kt4][64][8]  B-frags OUT (outw)
#define OFF_W2 77824   // [nt2][kt4][64][8]  B-frags X3 (fc2w)
#define HYPE 81920
#define WS_FLAG_OFF 327680  // int flag: mask dtype (1 => int32)

__device__ __forceinline__ unsigned short f2bf(float f) {
  unsigned u = __float_as_uint(f);
  u += 0x7fffu + ((u >> 16) & 1u);  // RNE
  return (unsigned short)(u >> 16);
}

// Store one 16x16 C-tile column (4 f32, rows row0+0..3, col) as bf16 into
// LDS row-major [..][ST]. Pairs lanes (col, col^1) via shfl so every dword
// is written by exactly one lane.
__device__ __forceinline__ void ctile_store(unsigned short* dst, int row0,
                                            int col, f32x4 v) {
  unsigned short m0 = f2bf(v[0]), m1 = f2bf(v[1]), m2 = f2bf(v[2]),
                 m3 = f2bf(v[3]);
  unsigned x = (unsigned)m0 | ((unsigned)m1 << 16);
  unsigned y = (unsigned)m2 | ((unsigned)m3 << 16);
  unsigned ox = (unsigned)__shfl_xor((int)x, 1);
  unsigned oy = (unsigned)__shfl_xor((int)y, 1);
  unsigned w0, w1;
  int ra;
  if ((threadIdx.x & 1) == 0) {
    ra = 0;
    w0 = (x & 0xffffu) | (ox << 16);
    w1 = (x >> 16) | (ox & 0xffff0000u);
  } else {
    ra = 2;
    w0 = (oy & 0xffffu) | (y << 16);
    w1 = (oy >> 16) | (y & 0xffff0000u);
  }
  *(unsigned*)(dst + (row0 + ra) * ST + (col & ~1)) = w0;
  *(unsigned*)(dst + (row0 + ra + 1) * ST + (col & ~1)) = w1;
}

// ---- prep: 160 work blocks (one float4/thread, source-order) + 1 mask blk
__global__ void prep_kernel(const float* __restrict__ w_fc1w,
                            const float* __restrict__ w_inw,
                            const float* __restrict__ w_outw,
                            const float* __restrict__ w_fc2w,
                            const float* __restrict__ v_fc1w,
                            const float* __restrict__ v_inw,
                            const float* __restrict__ v_outw,
                            const float* __restrict__ v_fc2w,
                            const unsigned char* __restrict__ mask,
                            unsigned short* __restrict__ ws,
                            int* __restrict__ flag) {
  if (blockIdx.x == 160) {
    // int32 0/1 data => every byte at offset %4!=0 is zero over first 4KB.
    const uint4 v = *(const uint4*)(mask + threadIdx.x * 16);
    const unsigned nz = (v.x | v.y | v.z | v.w) & 0xffffff00u;
    const int any = __syncthreads_or((int)(nz != 0));
    if (threadIdx.x == 0) *flag = (any == 0) ? 1 : 0;
    return;
  }
  const int g = blockIdx.x * 256 + threadIdx.x;  // 0 .. 40959
  const int p = (g >= 20480) ? 1 : 0;
  const int off = (g - p * 20480) * 4;  // aligned 4-elem group, one segment
  const float* fc1w = p ? v_fc1w : w_fc1w;
  const float* inw = p ? v_inw : w_inw;
  const float* outw = p ? v_outw : w_outw;
  const float* fc2w = p ? v_fc2w : w_fc2w;
  unsigned short* wsp = ws + p * HYPE;

  float4 v4;
  if (off < OFF_WQ) {
    v4 = *(const float4*)(fc1w + off);
#pragma unroll
    for (int r = 0; r < 4; ++r) {
      const int oe = off + r;
      const int k = oe >> 7, n = oe & 127;
      const int kt = k >> 5, kr = k & 31, j = kr & 7, khi = kr >> 3;
      const int nt = n >> 4, lo = n & 15;
      wsp[OFF_W1 + (nt * 3 + kt) * 512 + (khi * 16 + lo) * 8 + j] =
          f2bf(((const float*)&v4)[r]);
    }
  } else if (off < OFF_WK) {
    const int i = off - OFF_WQ;
    v4 = *(const float4*)(inw + (i >> 7) * 384 + (i & 127));
#pragma unroll
    for (int r = 0; r < 4; ++r) {
      const int ie = i + r;
      const int k = ie >> 7, n = ie & 127;
      const int kt = k >> 5, kr = k & 31, j = kr & 7, khi = kr >> 3;
      const int nt = n >> 4, lo = n & 15;
      wsp[OFF_WQ + (nt * 4 + kt) * 512 + (khi * 16 + lo) * 8 + j] =
          f2bf(((const float*)&v4)[r] * 0.17677669529663687f);
    }
  } else if (off < OFF_WV) {
    const int i = off - OFF_WK;
    v4 = *(const float4*)(inw + (i >> 7) * 384 + 128 + (i & 127));
#pragma unroll
    for (int r = 0; r < 4; ++r) {
      const int ie = i + r;
      const int m = ie >> 7, c = ie & 127;
      const int h = c >> 5, d = c & 31;
      const int nt = m >> 4;
      const int l = (d >> 3) * 16 + (m & 15);
      wsp[OFF_WK + (h * 8 + nt) * 512 + l * 8 + (d & 7)] =
          f2bf(((const float*)&v4)[r]);
    }
  } else if (off < OFF_WO) {
    const int i = off - OFF_WV;
    v4 = *(const float4*)(inw + (i >> 7) * 384 + 256 + (i & 127));
#pragma unroll
    for (int r = 0; r < 4; ++r) {
      const int ie = i + r;
      const int m = ie >> 7, c = ie & 127;
      const int h = c >> 5, d = c & 31;
      const int kt = m >> 5, mr = m & 31, j = mr & 7, mhi = mr >> 3;
      const int mt = d >> 4, lo = d & 15;
      wsp[OFF_WV + ((h * 2 + mt) * 4 + kt) * 512 + (mhi * 16 + lo) * 8 + j] =
          f2bf(((const float*)&v4)[r]);
    }
  } else if (off < OFF_W2) {
    const int i = off - OFF_WO;
    v4 = *(const float4*)(outw + i);
#pragma unroll
    for (int r = 0; r < 4; ++r) {
      const int ie = i + r;
      const int k = ie >> 7, n = ie & 127;
      const int kt = k >> 5, kr = k & 31, j = kr & 7, khi = kr >> 3;
      const int nt = n >> 4, lo = n & 15;
      wsp[OFF_WO + (nt * 4 + kt) * 512 + (khi * 16 + lo) * 8 + j] =
          f2bf(((const float*)&v4)[r]);
    }
  } else {
    const int i = off - OFF_W2;
    v4 = *(const float4*)(fc2w + i);
#pragma unroll
    for (int r = 0; r < 4; ++r) {
      const int ie = i + r;
      const int k = ie >> 5, n = ie & 31;
      const int kt = k >> 5, kr = k & 31, j = kr & 7, khi = kr >> 3;
      const int nt = n >> 4, lo = n & 15;
      wsp[OFF_W2 + (nt * 4 + kt) * 512 + (khi * 16 + lo) * 8 + j] =
          f2bf(((const float*)&v4)[r]);
    }
  }
}

// LDS (bytes) — R3 layout: sx1 [128][136]bf16 0..34816 | sQ/sout
// 34816..39168 | sqw 39168..43520 | sW 43520..47872 | sVT [32][136]
// 47872..56576 | sattn 56576..60928 | sred f2[64] 60928..61440 |
// sres f32[32] 61440..61568 | sm u8[128] 61568..61696
#define SMEM_BYTES 61696

__global__ __launch_bounds__(256, 2) void qmix_mfma(
    const float* __restrict__ agent_qs, const float* __restrict__ entities,
    const unsigned char* __restrict__ emask_g,
    const unsigned short* __restrict__ wsw, const int* __restrict__ mflag,
    const float* __restrict__ w_fc1b, const float* __restrict__ w_outb,
    const float* __restrict__ w_fc2b, const float* __restrict__ v_fc1b,
    const float* __restrict__ v_outb, const float* __restrict__ v_fc2b,
    float* __restrict__ out_g) {
  const int t = threadIdx.x;
  const int wv = t >> 6;
  const int ln = t & 63;
  const int lr = ln & 15;
  const int lq = ln >> 4;
  const int b = blockIdx.x;
  const float* ents = entities + (size_t)b * (NEn * EDm);

  __shared__ __align__(16) unsigned char smem[SMEM_BYTES];
  unsigned short* sx1 = (unsigned short*)smem;
  unsigned short* sQ = sx1 + 17408;  // also sout after head loop
  unsigned short* sqw = sx1 + 19584;
  unsigned short* sW = sx1 + 21760;
  unsigned short* sVT = sx1 + 23936;
  unsigned short* sattn = sx1 + 28288;
  float2* sred = (float2*)(smem + 60928);
  float* sredf = (float*)(smem + 60928);
  float* sres = (float*)(smem + 61440);
  unsigned char* sm = smem + 61568;

  // ---- entity mask (dtype-normalized) ----
  const int is_i32 = *mflag;
  int mv = 1;
  if (t < NEn) {
    if (is_i32)
      mv = (((const int*)emask_g)[(size_t)b * NEn + t] != 0) ? 1 : 0;
    else
      mv = (emask_g[(size_t)b * NEn + t] != 0) ? 1 : 0;
    sm[t] = (unsigned char)mv;
  }
  const int allE = __syncthreads_and(mv);

  for (int p = 0; p < 2; ++p) {
    const unsigned short* wsb = wsw + (size_t)p * HYPE;
    const float* fc1b = p ? v_fc1b : w_fc1b;
    const float* outb = p ? v_outb : w_outb;
    const float* fc2b = p ? v_fc2b : w_fc2b;

    // ---- Phase A: x1 = relu(E @ W1 + b) -> sx1 bf16 [e][m] ----
    {
#pragma unroll
      for (int mi = 0; mi < 2; ++mi) {
        const int mt = wv * 2 + mi;
        bf16x8 af[3];
        const float* erow = ents + (mt * 16 + lr) * EDm + lq * 8;
#pragma unroll
        for (int kt = 0; kt < 3; ++kt) {
          float4 u = *(const float4*)(erow + kt * 32);
          float4 v = *(const float4*)(erow + kt * 32 + 4);
          bf16x8 a;
          a[0] = (short)f2bf(u.x); a[1] = (short)f2bf(u.y);
          a[2] = (short)f2bf(u.z); a[3] = (short)f2bf(u.w);
          a[4] = (short)f2bf(v.x); a[5] = (short)f2bf(v.y);
          a[6] = (short)f2bf(v.z); a[7] = (short)f2bf(v.w);
          af[kt] = a;
        }
        for (int nt = 0; nt < 8; ++nt) {
          f32x4 acc = {0.f, 0.f, 0.f, 0.f};
          const unsigned short* bp = wsb + OFF_W1 + (nt * 3) * 512 + ln * 8;
#pragma unroll
          for (int kt = 0; kt < 3; ++kt)
            acc = MFMA(af[kt], *(const bf16x8*)(bp + kt * 512), acc);
          const float bias = fc1b[nt * 16 + lr];
          f32x4 r;
          r[0] = fmaxf(acc[0] + bias, 0.f); r[1] = fmaxf(acc[1] + bias, 0.f);
          r[2] = fmaxf(acc[2] + bias, 0.f); r[3] = fmaxf(acc[3] + bias, 0.f);
          ctile_store(sx1, mt * 16 + lq * 4, nt * 16 + lr, r);
        }
      }
    }
    __syncthreads();

    // ---- Q = x1[0:16] @ Wq' (scaled) -> sQ [16][128] ----
    {
      bf16x8 aq[4];
#pragma unroll
      for (int kt = 0; kt < 4; ++kt)
        aq[kt] = *(const bf16x8*)(sx1 + lr * ST + kt * 32 + lq * 8);
#pragma unroll
      for (int ni = 0; ni < 2; ++ni) {
        const int nt = wv * 2 + ni;
        f32x4 acc = {0.f, 0.f, 0.f, 0.f};
        const unsigned short* bp = wsb + OFF_WQ + (nt * 4) * 512 + ln * 8;
#pragma unroll
        for (int kt = 0; kt < 4; ++kt)
          acc = MFMA(aq[kt], *(const bf16x8*)(bp + kt * 512), acc);
        ctile_store(sQ, lq * 4, nt * 16 + lr, acc);
      }
    }
    __syncthreads();

    for (int h = 0; h < 4; ++h) {
      // ---- merged: qW = Q_h @ Wk_h^T -> sqw, V^T_h = Wv_h^T @ x1^T -> sVT
      {
        bf16x8 aQ = *(const bf16x8*)(sQ + lr * ST + h * 32 + lq * 8);
#pragma unroll
        for (int ni = 0; ni < 2; ++ni) {
          const int nt = wv * 2 + ni;
          bf16x8 bk =
              *(const bf16x8*)(wsb + OFF_WK + (h * 8 + nt) * 512 + ln * 8);
          f32x4 acc = {0.f, 0.f, 0.f, 0.f};
          acc = MFMA(aQ, bk, acc);
          ctile_store(sqw, lq * 4, nt * 16 + lr, acc);
        }
        bf16x8 av[2][4];
#pragma unroll
        for (int mt = 0; mt < 2; ++mt)
#pragma unroll
          for (int kt = 0; kt < 4; ++kt)
            av[mt][kt] = *(const bf16x8*)(wsb + OFF_WV +
                                          (((h * 2 + mt) * 4) + kt) * 512 +
                                          ln * 8);
#pragma unroll
        for (int ni = 0; ni < 2; ++ni) {
          const int nt = wv * 2 + ni;
          bf16x8 bx[4];
#pragma unroll
          for (int kt = 0; kt < 4; ++kt)
            bx[kt] =
                *(const bf16x8*)(sx1 + (nt * 16 + lr) * ST + kt * 32 + lq * 8);
#pragma unroll
          for (int mt = 0; mt < 2; ++mt) {
            f32x4 acc = {0.f, 0.f, 0.f, 0.f};
#pragma unroll
            for (int kt = 0; kt < 4; ++kt) acc = MFMA(av[mt][kt], bx[kt], acc);
            ctile_store(sVT, mt * 16 + lq * 4, nt * 16 + lr, acc);
          }
        }
      }
      __syncthreads();

      // ---- logits = qW @ x1^T, mask cols, wave-local softmax stats ----
      float mx[4], ex0[4], ex1[4];
      {
        bf16x8 aw[4];
#pragma unroll
        for (int kt = 0; kt < 4; ++kt)
          aw[kt] = *(const bf16x8*)(sqw + lr * ST + kt * 32 + lq * 8);
        f32x4 a0 = {0.f, 0.f, 0.f, 0.f}, a1 = {0.f, 0.f, 0.f, 0.f};
        const int nt0 = wv * 2, nt1 = nt0 + 1;
#pragma unroll
        for (int kt = 0; kt < 4; ++kt) {
          bf16x8 b0 =
              *(const bf16x8*)(sx1 + (nt0 * 16 + lr) * ST + kt * 32 + lq * 8);
          bf16x8 b1 =
              *(const bf16x8*)(sx1 + (nt1 * 16 + lr) * ST + kt * 32 + lq * 8);
          a0 = MFMA(aw[kt], b0, a0);
          a1 = MFMA(aw[kt], b1, a1);
        }
        const int e0m = sm[nt0 * 16 + lr], e1m = sm[nt1 * 16 + lr];
        float l0[4], l1[4];
#pragma unroll
        for (int r = 0; r < 4; ++r) {
          l0[r] = e0m ? -1e9f : a0[r];
          l1[r] = e1m ? -1e9f : a1[r];
          mx[r] = fmaxf(l0[r], l1[r]);
        }
#pragma unroll
        for (int k = 1; k < 16; k <<= 1)
#pragma unroll
          for (int r = 0; r < 4; ++r)
            mx[r] = fmaxf(mx[r], __shfl_xor(mx[r], k));
        float sl[4];
#pragma unroll
        for (int r = 0; r < 4; ++r) {
          ex0[r] = __expf(l0[r] - mx[r]);
          ex1[r] = __expf(l1[r] - mx[r]);
          sl[r] = ex0[r] + ex1[r];
        }
#pragma unroll
        for (int k = 1; k < 16; k <<= 1)
#pragma unroll
          for (int r = 0; r < 4; ++r) sl[r] += __shfl_xor(sl[r], k);
        if (lr == 0) {
#pragma unroll
          for (int r = 0; r < 4; ++r)
            sred[wv * 16 + lq * 4 + r] = make_float2(mx[r], sl[r]);
        }
      }
      __syncthreads();

      // ---- softmax finish -> sW bf16 ----
      {
        f32x4 w0v, w1v;
#pragma unroll
        for (int r = 0; r < 4; ++r) {
          const int row = lq * 4 + r;
          float2 p0 = sred[row], p1 = sred[16 + row], p2 = sred[32 + row],
                 p3 = sred[48 + row];
          float M = fmaxf(fmaxf(p0.x, p1.x), fmaxf(p2.x, p3.x));
          float S = __expf(p0.x - M) * p0.y + __expf(p1.x - M) * p1.y +
                    __expf(p2.x - M) * p2.y + __expf(p3.x - M) * p3.y;
          const float sc = ((int)sm[row] | allE) ? 0.f : (1.f / S);
          const float f = __expf(mx[r] - M) * sc;
          w0v[r] = ex0[r] * f;
          w1v[r] = ex1[r] * f;
        }
        ctile_store(sW, lq * 4, wv * 32 + lr, w0v);
        ctile_store(sW, lq * 4, wv * 32 + 16 + lr, w1v);
      }
      __syncthreads();

      // ---- attn_h = w @ V_h -> sattn cols h*32.. (waves 0,1) ----
      if (wv < 2) {
        bf16x8 afr[4];
#pragma unroll
        for (int kt = 0; kt < 4; ++kt)
          afr[kt] = *(const bf16x8*)(sW + lr * ST + kt * 32 + lq * 8);
        f32x4 acc = {0.f, 0.f, 0.f, 0.f};
#pragma unroll
        for (int kt = 0; kt < 4; ++kt) {
          bf16x8 bfr =
              *(const bf16x8*)(sVT + (wv * 16 + lr) * ST + kt * 32 + lq * 8);
          acc = MFMA(afr[kt], bfr, acc);
        }
        ctile_store(sattn, lq * 4, h * 32 + wv * 16 + lr, acc);
      }
      __syncthreads();
    }  // heads

    // ---- OUT = attn @ Wo + bo -> sQ (== sout) ----
    {
      bf16x8 aa[4];
#pragma unroll
      for (int kt = 0; kt < 4; ++kt)
        aa[kt] = *(const bf16x8*)(sattn + lr * ST + kt * 32 + lq * 8);
#pragma unroll
      for (int ni = 0; ni < 2; ++ni) {
        const int nt = wv * 2 + ni;
        f32x4 acc = {0.f, 0.f, 0.f, 0.f};
        const unsigned short* bp = wsb + OFF_WO + (nt * 4) * 512 + ln * 8;
#pragma unroll
        for (int kt = 0; kt < 4; ++kt)
          acc = MFMA(aa[kt], *(const bf16x8*)(bp + kt * 512), acc);
        const float bj = outb[nt * 16 + lr];
        f32x4 r;
        r[0] = acc[0] + bj; r[1] = acc[1] + bj;
        r[2] = acc[2] + bj; r[3] = acc[3] + bj;
        ctile_store(sQ, lq * 4, nt * 16 + lr, r);
      }
    }
    __syncthreads();

    // ---- X3 = out @ fc2 + b, mask rows, row-sum (waves 0,1) ----
    if (wv < 2) {
      bf16x8 ao[4];
#pragma unroll
      for (int kt = 0; kt < 4; ++kt)
        ao[kt] = *(const bf16x8*)(sQ + lr * ST + kt * 32 + lq * 8);
      f32x4 acc = {0.f, 0.f, 0.f, 0.f};
      const unsigned short* bp = wsb + OFF_W2 + (wv * 4) * 512 + ln * 8;
#pragma unroll
      for (int kt = 0; kt < 4; ++kt)
        acc = MFMA(ao[kt], *(const bf16x8*)(bp + kt * 512), acc);
      const float bc = fc2b[wv * 16 + lr];
      float rs[4];
#pragma unroll
      for (int r = 0; r < 4; ++r) {
        const int row = lq * 4 + r;
        rs[r] = sm[row] ? 0.f : (acc[r] + bc);
      }
#pragma unroll
      for (int k = 1; k < 16; k <<= 1)
#pragma unroll
        for (int r = 0; r < 4; ++r) rs[r] += __shfl_xor(rs[r], k);
      if (lr == 0) {
#pragma unroll
        for (int r = 0; r < 4; ++r) sredf[wv * 16 + lq * 4 + r] = rs[r];
      }
    }
    __syncthreads();
    if (t < 16) {
      const float s = sredf[t] + sredf[16 + t];
      if (p == 0)
        sres[t] = fabsf(s) * (1.f / 32.f);
      else
        sres[16 + t] = s;
    }
    __syncthreads();
  }  // p

  if (t == 0) {
    const float* qs = agent_qs + (size_t)b * NA;
    float tot = 0.f, vs = 0.f;
#pragma unroll
    for (int q = 0; q < NA; ++q) {
      tot += qs[q] * sres[q];
      vs += sres[16 + q];
    }
    out_g[b] = tot + vs * (1.f / 512.f);
  }
}

extern "C" void kernel_launch(void* const* d_in, const int* in_sizes, int n_in,
                              void* d_out, int out_size, void* d_ws,
                              size_t ws_size, hipStream_t stream) {
  (void)n_in; (void)out_size; (void)ws_size;
  const int nb = in_sizes[0] / NA;  // BS*T = 1600
  unsigned short* wsw = (unsigned short*)d_ws;
  int* mflag = (int*)((char*)d_ws + WS_FLAG_OFF);

  hipLaunchKernelGGL(prep_kernel, dim3(161), dim3(256), 0, stream,
                     (const float*)d_in[3], (const float*)d_in[5],
                     (const float*)d_in[6], (const float*)d_in[8],
                     (const float*)d_in[10], (const float*)d_in[12],
                     (const float*)d_in[13], (const float*)d_in[15],
                     (const unsigned char*)d_in[2], wsw, mflag);
  hipLaunchKernelGGL(qmix_mfma, dim3(nb), dim3(256), 0, stream,
                     (const float*)d_in[0], (const float*)d_in[1],
                     (const unsigned char*)d_in[2], (const unsigned short*)wsw,
                     (const int*)mflag, (const float*)d_in[4],
                     (const float*)d_in[7], (const float*)d_in[9],
                     (const float*)d_in[11], (const float*)d_in[14],
                     (const float*)d_in[16], (float*)d_out);
}

// Round 8
// 268.626 us; speedup vs baseline: 1.3381x; 1.1252x over previous
//
#include <hip/hip_runtime.h>

// LinearFlexQMixer MI355X — round 8: wave-per-head, barrier-starved.
// Heads are independent -> wave wv owns head wv: qW -> full-width logits ->
// in-wave softmax -> V^T -> attn with ZERO __syncthreads (per-wave LDS slice
// transposes, lgkmcnt only). V^T overlays the dead sx1 region after one
// barrier. Barriers/block: 43 -> 10. Prep kernel unchanged from R7.

#define NA 16
#define NEn 128
#define EDm 96
#define ST 136  // LDS row stride (shorts); 272B rows -> <=2-way conflicts

typedef __attribute__((ext_vector_type(8))) short bf16x8;
typedef __attribute__((ext_vector_type(4))) float f32x4;

#define MFMA(a, b, c) __builtin_amdgcn_mfma_f32_16x16x32_bf16((a), (b), (c), 0, 0, 0)
#define LGKM0() __asm__ volatile("s_waitcnt lgkmcnt(0)" ::: "memory")

// d_ws layout (bf16 elems), per hypernet p at p*HYPE:
#define OFF_W1 0       // [nt8][kt3][64][8]  B-frags Phase A (fc1w)
#define OFF_WQ 12288   // [nt8][kt4][64][8]  B-frags Q (inw cols 0:128, pre-scaled)
#define OFF_WK 28672   // [h4][nt8][64][8]   B-frags qW (Wk^T per head, K=32)
#define OFF_WV 45056   // [h4][mt2][kt4][64][8] A-frags V^T (Wv^T per head)
#define OFF_WO 61440   // [nt8][kt4][64][8]  B-frags OUT (outw)
#define OFF_W2 77824   // [nt2][kt4][64][8]  B-frags X3 (fc2w)
#define HYPE 81920
#define WS_FLAG_OFF 327680  // int flag: mask dtype (1 => int32)

__device__ __forceinline__ unsigned short f2bf(float f) {
  unsigned u = __float_as_uint(f);
  u += 0x7fffu + ((u >> 16) & 1u);  // RNE
  return (unsigned short)(u >> 16);
}

// Store one 16x16 C-tile column (4 f32, rows row0+0..3, col) as bf16 into
// LDS row-major [..][ST]. Pairs lanes (col, col^1) via shfl so every dword
// is written by exactly one lane. Full-wave calls only.
__device__ __forceinline__ void ctile_store(unsigned short* dst, int row0,
                                            int col, f32x4 v) {
  unsigned short m0 = f2bf(v[0]), m1 = f2bf(v[1]), m2 = f2bf(v[2]),
                 m3 = f2bf(v[3]);
  unsigned x = (unsigned)m0 | ((unsigned)m1 << 16);
  unsigned y = (unsigned)m2 | ((unsigned)m3 << 16);
  unsigned ox = (unsigned)__shfl_xor((int)x, 1);
  unsigned oy = (unsigned)__shfl_xor((int)y, 1);
  unsigned w0, w1;
  int ra;
  if ((threadIdx.x & 1) == 0) {
    ra = 0;
    w0 = (x & 0xffffu) | (ox << 16);
    w1 = (x >> 16) | (ox & 0xffff0000u);
  } else {
    ra = 2;
    w0 = (oy & 0xffffu) | (y << 16);
    w1 = (oy >> 16) | (y & 0xffff0000u);
  }
  *(unsigned*)(dst + (row0 + ra) * ST + (col & ~1)) = w0;
  *(unsigned*)(dst + (row0 + ra + 1) * ST + (col & ~1)) = w1;
}

// ---- prep: 160 work blocks (one float4/thread, source-order) + 1 mask blk
__global__ void prep_kernel(const float* __restrict__ w_fc1w,
                            const float* __restrict__ w_inw,
                            const float* __restrict__ w_outw,
                            const float* __restrict__ w_fc2w,
                            const float* __restrict__ v_fc1w,
                            const float* __restrict__ v_inw,
                            const float* __restrict__ v_outw,
                            const float* __restrict__ v_fc2w,
                            const unsigned char* __restrict__ mask,
                            unsigned short* __restrict__ ws,
                            int* __restrict__ flag) {
  if (blockIdx.x == 160) {
    const uint4 v = *(const uint4*)(mask + threadIdx.x * 16);
    const unsigned nz = (v.x | v.y | v.z | v.w) & 0xffffff00u;
    const int any = __syncthreads_or((int)(nz != 0));
    if (threadIdx.x == 0) *flag = (any == 0) ? 1 : 0;
    return;
  }
  const int g = blockIdx.x * 256 + threadIdx.x;  // 0 .. 40959
  const int p = (g >= 20480) ? 1 : 0;
  const int off = (g - p * 20480) * 4;
  const float* fc1w = p ? v_fc1w : w_fc1w;
  const float* inw = p ? v_inw : w_inw;
  const float* outw = p ? v_outw : w_outw;
  const float* fc2w = p ? v_fc2w : w_fc2w;
  unsigned short* wsp = ws + p * HYPE;

  float4 v4;
  if (off < OFF_WQ) {
    v4 = *(const float4*)(fc1w + off);
#pragma unroll
    for (int r = 0; r < 4; ++r) {
      const int oe = off + r;
      const int k = oe >> 7, n = oe & 127;
      const int kt = k >> 5, kr = k & 31, j = kr & 7, khi = kr >> 3;
      const int nt = n >> 4, lo = n & 15;
      wsp[OFF_W1 + (nt * 3 + kt) * 512 + (khi * 16 + lo) * 8 + j] =
          f2bf(((const float*)&v4)[r]);
    }
  } else if (off < OFF_WK) {
    const int i = off - OFF_WQ;
    v4 = *(const float4*)(inw + (i >> 7) * 384 + (i & 127));
#pragma unroll
    for (int r = 0; r < 4; ++r) {
      const int ie = i + r;
      const int k = ie >> 7, n = ie & 127;
      const int kt = k >> 5, kr = k & 31, j = kr & 7, khi = kr >> 3;
      const int nt = n >> 4, lo = n & 15;
      wsp[OFF_WQ + (nt * 4 + kt) * 512 + (khi * 16 + lo) * 8 + j] =
          f2bf(((const float*)&v4)[r] * 0.17677669529663687f);
    }
  } else if (off < OFF_WV) {
    const int i = off - OFF_WK;
    v4 = *(const float4*)(inw + (i >> 7) * 384 + 128 + (i & 127));
#pragma unroll
    for (int r = 0; r < 4; ++r) {
      const int ie = i + r;
      const int m = ie >> 7, c = ie & 127;
      const int h = c >> 5, d = c & 31;
      const int nt = m >> 4;
      const int l = (d >> 3) * 16 + (m & 15);
      wsp[OFF_WK + (h * 8 + nt) * 512 + l * 8 + (d & 7)] =
          f2bf(((const float*)&v4)[r]);
    }
  } else if (off < OFF_WO) {
    const int i = off - OFF_WV;
    v4 = *(const float4*)(inw + (i >> 7) * 384 + 256 + (i & 127));
#pragma unroll
    for (int r = 0; r < 4; ++r) {
      const int ie = i + r;
      const int m = ie >> 7, c = ie & 127;
      const int h = c >> 5, d = c & 31;
      const int kt = m >> 5, mr = m & 31, j = mr & 7, mhi = mr >> 3;
      const int mt = d >> 4, lo = d & 15;
      wsp[OFF_WV + ((h * 2 + mt) * 4 + kt) * 512 + (mhi * 16 + lo) * 8 + j] =
          f2bf(((const float*)&v4)[r]);
    }
  } else if (off < OFF_W2) {
    const int i = off - OFF_WO;
    v4 = *(const float4*)(outw + i);
#pragma unroll
    for (int r = 0; r < 4; ++r) {
      const int ie = i + r;
      const int k = ie >> 7, n = ie & 127;
      const int kt = k >> 5, kr = k & 31, j = kr & 7, khi = kr >> 3;
      const int nt = n >> 4, lo = n & 15;
      wsp[OFF_WO + (nt * 4 + kt) * 512 + (khi * 16 + lo) * 8 + j] =
          f2bf(((const float*)&v4)[r]);
    }
  } else {
    const int i = off - OFF_W2;
    v4 = *(const float4*)(fc2w + i);
#pragma unroll
    for (int r = 0; r < 4; ++r) {
      const int ie = i + r;
      const int k = ie >> 5, n = ie & 31;
      const int kt = k >> 5, kr = k & 31, j = kr & 7, khi = kr >> 3;
      const int nt = n >> 4, lo = n & 15;
      wsp[OFF_W2 + (nt * 4 + kt) * 512 + (khi * 16 + lo) * 8 + j] =
          f2bf(((const float*)&v4)[r]);
    }
  }
}

// LDS (bytes):
//   sx1 / vtbuf [128][136]bf16   0..34816  (x1, then V^T overlay rows h*32..)
//   sS  4x[16][136]              34816..52224  (per-wave scratch slice)
//   sattn [16][136]              52224..56576
//   sout  [16][136]              56576..60928
//   sres f32[32]                 60928..61056
//   sm   u8[128]                 61056..61184
#define SMEM_BYTES 61184

__global__ __launch_bounds__(256, 2) void qmix_mfma(
    const float* __restrict__ agent_qs, const float* __restrict__ entities,
    const unsigned char* __restrict__ emask_g,
    const unsigned short* __restrict__ wsw, const int* __restrict__ mflag,
    const float* __restrict__ w_fc1b, const float* __restrict__ w_outb,
    const float* __restrict__ w_fc2b, const float* __restrict__ v_fc1b,
    const float* __restrict__ v_outb, const float* __restrict__ v_fc2b,
    float* __restrict__ out_g) {
  const int t = threadIdx.x;
  const int wv = t >> 6;  // wave == head
  const int ln = t & 63;
  const int lr = ln & 15;
  const int lq = ln >> 4;
  const int b = blockIdx.x;
  const float* ents = entities + (size_t)b * (NEn * EDm);

  __shared__ __align__(16) unsigned char smem[SMEM_BYTES];
  unsigned short* sx1 = (unsigned short*)smem;         // also vtbuf
  unsigned short* sSlice = sx1 + 17408;                // 4 slices
  unsigned short* sattn = sx1 + 26112;
  unsigned short* sout = sx1 + 28288;
  float* sres = (float*)(smem + 60928);
  unsigned char* sm = smem + 61056;
  unsigned short* sS = sSlice + wv * 16 * ST;  // this wave's slice

  // ---- entity mask (dtype-normalized) ----
  const int is_i32 = *mflag;
  int mv = 1;
  if (t < NEn) {
    if (is_i32)
      mv = (((const int*)emask_g)[(size_t)b * NEn + t] != 0) ? 1 : 0;
    else
      mv = (emask_g[(size_t)b * NEn + t] != 0) ? 1 : 0;
    sm[t] = (unsigned char)mv;
  }
  const int allE = __syncthreads_and(mv);

  for (int p = 0; p < 2; ++p) {
    const unsigned short* wsb = wsw + (size_t)p * HYPE;
    const float* fc1b = p ? v_fc1b : w_fc1b;
    const float* outb = p ? v_outb : w_outb;
    const float* fc2b = p ? v_fc2b : w_fc2b;

    // ---- Phase A (co-op): x1 = relu(E @ W1 + b) -> sx1 [e][m] ----
    {
#pragma unroll
      for (int mi = 0; mi < 2; ++mi) {
        const int mt = wv * 2 + mi;
        bf16x8 af[3];
        const float* erow = ents + (mt * 16 + lr) * EDm + lq * 8;
#pragma unroll
        for (int kt = 0; kt < 3; ++kt) {
          float4 u = *(const float4*)(erow + kt * 32);
          float4 v = *(const float4*)(erow + kt * 32 + 4);
          bf16x8 a;
          a[0] = (short)f2bf(u.x); a[1] = (short)f2bf(u.y);
          a[2] = (short)f2bf(u.z); a[3] = (short)f2bf(u.w);
          a[4] = (short)f2bf(v.x); a[5] = (short)f2bf(v.y);
          a[6] = (short)f2bf(v.z); a[7] = (short)f2bf(v.w);
          af[kt] = a;
        }
        for (int nt = 0; nt < 8; ++nt) {
          f32x4 acc = {0.f, 0.f, 0.f, 0.f};
          const unsigned short* bp = wsb + OFF_W1 + (nt * 3) * 512 + ln * 8;
#pragma unroll
          for (int kt = 0; kt < 3; ++kt)
            acc = MFMA(af[kt], *(const bf16x8*)(bp + kt * 512), acc);
          const float bias = fc1b[nt * 16 + lr];
          f32x4 r;
          r[0] = fmaxf(acc[0] + bias, 0.f); r[1] = fmaxf(acc[1] + bias, 0.f);
          r[2] = fmaxf(acc[2] + bias, 0.f); r[3] = fmaxf(acc[3] + bias, 0.f);
          ctile_store(sx1, mt * 16 + lq * 4, nt * 16 + lr, r);
        }
      }
    }
    __syncthreads();  // B1: x1 complete

    // ---- Q (own head): Q_h[q][d] -> transpose via slice -> aQ ----
    {
      bf16x8 aq[4];
#pragma unroll
      for (int kt = 0; kt < 4; ++kt)
        aq[kt] = *(const bf16x8*)(sx1 + lr * ST + kt * 32 + lq * 8);
#pragma unroll
      for (int ni = 0; ni < 2; ++ni) {
        const int nt = wv * 2 + ni;
        f32x4 acc = {0.f, 0.f, 0.f, 0.f};
        const unsigned short* bp = wsb + OFF_WQ + (nt * 4) * 512 + ln * 8;
#pragma unroll
        for (int kt = 0; kt < 4; ++kt)
          acc = MFMA(aq[kt], *(const bf16x8*)(bp + kt * 512), acc);
        ctile_store(sS, lq * 4, ni * 16 + lr, acc);  // local d cols 0..31
      }
    }
    LGKM0();
    const bf16x8 aQ = *(const bf16x8*)(sS + lr * ST + lq * 8);  // A[q][d0..31]

    // ---- qW = Q_h @ Wk_h^T (8 m-tiles) -> transpose -> aw ----
    {
      f32x4 Cw[8];
#pragma unroll
      for (int nt = 0; nt < 8; ++nt) {
        f32x4 acc = {0.f, 0.f, 0.f, 0.f};
        Cw[nt] = MFMA(aQ, *(const bf16x8*)(wsb + OFF_WK + (wv * 8 + nt) * 512 +
                                           ln * 8),
                      acc);
      }
#pragma unroll
      for (int nt = 0; nt < 8; ++nt)
        ctile_store(sS, lq * 4, nt * 16 + lr, Cw[nt]);
    }
    LGKM0();
    bf16x8 aw[4];
#pragma unroll
    for (int kt = 0; kt < 4; ++kt)
      aw[kt] = *(const bf16x8*)(sS + lr * ST + kt * 32 + lq * 8);

    // ---- logits (full width, in-wave): Cl[nt] = qW @ x1^T ----
    f32x4 Cl[8];
#pragma unroll
    for (int nt = 0; nt < 8; ++nt) {
      f32x4 acc = {0.f, 0.f, 0.f, 0.f};
#pragma unroll
      for (int kt = 0; kt < 4; ++kt) {
        const bf16x8 bx =
            *(const bf16x8*)(sx1 + (nt * 16 + lr) * ST + kt * 32 + lq * 8);
        acc = MFMA(aw[kt], bx, acc);
      }
      Cl[nt] = acc;
    }

    // ---- in-wave softmax over 128 cols ----
    {
      float lv[8][4];
#pragma unroll
      for (int nt = 0; nt < 8; ++nt) {
        const int eM = sm[nt * 16 + lr];
#pragma unroll
        for (int r = 0; r < 4; ++r) lv[nt][r] = eM ? -1e9f : Cl[nt][r];
      }
      float mx[4], sl[4];
#pragma unroll
      for (int r = 0; r < 4; ++r) {
        float m = lv[0][r];
#pragma unroll
        for (int nt = 1; nt < 8; ++nt) m = fmaxf(m, lv[nt][r]);
        mx[r] = m;
      }
#pragma unroll
      for (int k = 1; k < 16; k <<= 1)
#pragma unroll
        for (int r = 0; r < 4; ++r) mx[r] = fmaxf(mx[r], __shfl_xor(mx[r], k));
      float ex[8][4];
#pragma unroll
      for (int r = 0; r < 4; ++r) sl[r] = 0.f;
#pragma unroll
      for (int nt = 0; nt < 8; ++nt)
#pragma unroll
        for (int r = 0; r < 4; ++r) {
          ex[nt][r] = __expf(lv[nt][r] - mx[r]);
          sl[r] += ex[nt][r];
        }
#pragma unroll
      for (int k = 1; k < 16; k <<= 1)
#pragma unroll
        for (int r = 0; r < 4; ++r) sl[r] += __shfl_xor(sl[r], k);
      float sc[4];
#pragma unroll
      for (int r = 0; r < 4; ++r)
        sc[r] = ((int)sm[lq * 4 + r] | allE) ? 0.f : (1.f / sl[r]);
#pragma unroll
      for (int nt = 0; nt < 8; ++nt) {
        f32x4 wv4;
#pragma unroll
        for (int r = 0; r < 4; ++r) wv4[r] = ex[nt][r] * sc[r];
        ctile_store(sS, lq * 4, nt * 16 + lr, wv4);  // W, overwrites qW
      }
    }
    LGKM0();
    bf16x8 aw2[4];
#pragma unroll
    for (int kt = 0; kt < 4; ++kt)
      aw2[kt] = *(const bf16x8*)(sS + lr * ST + kt * 32 + lq * 8);

    // ---- V^T_h = Wv_h^T @ x1^T into regs (x1 still live) ----
    f32x4 Cv[2][8];
#pragma unroll
    for (int mt = 0; mt < 2; ++mt) {
      bf16x8 av[4];
#pragma unroll
      for (int kt = 0; kt < 4; ++kt)
        av[kt] = *(const bf16x8*)(wsb + OFF_WV +
                                  (((wv * 2 + mt) * 4) + kt) * 512 + ln * 8);
#pragma unroll
      for (int nt = 0; nt < 8; ++nt) {
        f32x4 acc = {0.f, 0.f, 0.f, 0.f};
#pragma unroll
        for (int kt = 0; kt < 4; ++kt) {
          const bf16x8 bx =
              *(const bf16x8*)(sx1 + (nt * 16 + lr) * ST + kt * 32 + lq * 8);
          acc = MFMA(av[kt], bx, acc);
        }
        Cv[mt][nt] = acc;
      }
    }
    __syncthreads();  // B2: x1 dead -> region becomes vtbuf

    // ---- write V^T into own 32-row band of vtbuf; attn = W @ V_h ----
    {
#pragma unroll
      for (int mt = 0; mt < 2; ++mt)
#pragma unroll
        for (int nt = 0; nt < 8; ++nt)
          ctile_store(sx1, wv * 32 + mt * 16 + lq * 4, nt * 16 + lr,
                      Cv[mt][nt]);
    }
    LGKM0();
    {
#pragma unroll
      for (int ntd = 0; ntd < 2; ++ntd) {
        f32x4 acc = {0.f, 0.f, 0.f, 0.f};
#pragma unroll
        for (int kt = 0; kt < 4; ++kt) {
          const bf16x8 bv = *(const bf16x8*)(sx1 + (wv * 32 + ntd * 16 + lr) *
                                                       ST +
                                             kt * 32 + lq * 8);
          acc = MFMA(aw2[kt], bv, acc);
        }
        ctile_store(sattn, lq * 4, wv * 32 + ntd * 16 + lr, acc);
      }
    }
    __syncthreads();  // B3: sattn complete

    // ---- OUT = attn @ Wo + bo -> sout (co-op, 2 n-tiles/wave) ----
    {
      bf16x8 aa[4];
#pragma unroll
      for (int kt = 0; kt < 4; ++kt)
        aa[kt] = *(const bf16x8*)(sattn + lr * ST + kt * 32 + lq * 8);
#pragma unroll
      for (int ni = 0; ni < 2; ++ni) {
        const int nt = wv * 2 + ni;
        f32x4 acc = {0.f, 0.f, 0.f, 0.f};
        const unsigned short* bp = wsb + OFF_WO + (nt * 4) * 512 + ln * 8;
#pragma unroll
        for (int kt = 0; kt < 4; ++kt)
          acc = MFMA(aa[kt], *(const bf16x8*)(bp + kt * 512), acc);
        const float bj = outb[nt * 16 + lr];
        f32x4 r;
        r[0] = acc[0] + bj; r[1] = acc[1] + bj;
        r[2] = acc[2] + bj; r[3] = acc[3] + bj;
        ctile_store(sout, lq * 4, nt * 16 + lr, r);
      }
    }
    __syncthreads();  // B4: sout complete

    // ---- X3 = out @ fc2 + b (redundant per wave), mask, row-sum ----
    {
      bf16x8 ao[4];
#pragma unroll
      for (int kt = 0; kt < 4; ++kt)
        ao[kt] = *(const bf16x8*)(sout + lr * ST + kt * 32 + lq * 8);
      f32x4 Cx[2];
#pragma unroll
      for (int nt = 0; nt < 2; ++nt) {
        f32x4 acc = {0.f, 0.f, 0.f, 0.f};
        const unsigned short* bp = wsb + OFF_W2 + (nt * 4) * 512 + ln * 8;
#pragma unroll
        for (int kt = 0; kt < 4; ++kt)
          acc = MFMA(ao[kt], *(const bf16x8*)(bp + kt * 512), acc);
        Cx[nt] = acc;
      }
      const float b0 = fc2b[lr], b1 = fc2b[16 + lr];
      float rs[4];
#pragma unroll
      for (int r = 0; r < 4; ++r) {
        const int row = lq * 4 + r;
        rs[r] = sm[row] ? 0.f : (Cx[0][r] + b0 + Cx[1][r] + b1);
      }
#pragma unroll
      for (int k = 1; k < 16; k <<= 1)
#pragma unroll
        for (int r = 0; r < 4; ++r) rs[r] += __shfl_xor(rs[r], k);
      if (wv == 0 && lr == 0) {
#pragma unroll
        for (int r = 0; r < 4; ++r) {
          const int q = lq * 4 + r;
          sres[p * 16 + q] = p ? rs[r] : fabsf(rs[r]) * (1.f / 32.f);
        }
      }
    }
  }  // p

  __syncthreads();
  if (t == 0) {
    const float* qs = agent_qs + (size_t)b * NA;
    float tot = 0.f, vs = 0.f;
#pragma unroll
    for (int q = 0; q < NA; ++q) {
      tot += qs[q] * sres[q];
      vs += sres[16 + q];
    }
    out_g[b] = tot + vs * (1.f / 512.f);
  }
}

extern "C" void kernel_launch(void* const* d_in, const int* in_sizes, int n_in,
                              void* d_out, int out_size, void* d_ws,
                              size_t ws_size, hipStream_t stream) {
  (void)n_in; (void)out_size; (void)ws_size;
  const int nb = in_sizes[0] / NA;  // BS*T = 1600
  unsigned short* wsw = (unsigned short*)d_ws;
  int* mflag = (int*)((char*)d_ws + WS_FLAG_OFF);

  hipLaunchKernelGGL(prep_kernel, dim3(161), dim3(256), 0, stream,
                     (const float*)d_in[3], (const float*)d_in[5],
                     (const float*)d_in[6], (const float*)d_in[8],
                     (const float*)d_in[10], (const float*)d_in[12],
                     (const float*)d_in[13], (const float*)d_in[15],
                     (const unsigned char*)d_in[2], wsw, mflag);
  hipLaunchKernelGGL(qmix_mfma, dim3(nb), dim3(256), 0, stream,
                     (const float*)d_in[0], (const float*)d_in[1],
                     (const unsigned char*)d_in[2], (const unsigned short*)wsw,
                     (const int*)mflag, (const float*)d_in[4],
                     (const float*)d_in[7], (const float*)d_in[9],
                     (const float*)d_in[11], (const float*)d_in[14],
                     (const float*)d_in[16], (float*)d_out);
}